// Round 11
// baseline (24.606 us; speedup 1.0000x reference)
//
#include <hip/hip_runtime.h>

// Problem constants (from reference setup_inputs)
#define BB   64
#define NQ   900
#define NC   256
#define NT   128

#define RPW  4    // rows per wave: one per 16-lane group
#define RPB  16   // rows per block (4 waves)
#define NCHUNK 57 // ceil(900/16); chunk 56: only wave 0 valid
#define GRIDY 8   // persistent: each block loops over 8 batches (64 = 8*8)

typedef float f32x2 __attribute__((ext_vector_type(2)));

// DPP butterfly add across a 16-lane group (VALU pipe, no LDS)
template<int CTRL>
__device__ __forceinline__ float dpp_add(float x) {
    int y = __builtin_amdgcn_update_dpp(0, __float_as_int(x), CTRL, 0xF, 0xF, true);
    return x + __int_as_float(y);
}

__device__ __forceinline__ float lane_bcast(float x, int l) {
    return __int_as_float(__builtin_amdgcn_readlane(__float_as_int(x), l));
}

__global__ __launch_bounds__(256) void matcher_kernel(
    const float* __restrict__ logits,   // [B, NQ, 256]
    const float* __restrict__ pboxes,   // [B, NQ, 4] cxcywh
    const int*   __restrict__ tlabels,  // [B, 128]
    const float* __restrict__ tboxes,   // [B, 128, 4] cxcywh
    float* __restrict__ out)            // [B, NQ, 128]
{
    constexpr float W_BBOX = 5.0f, W_GIOU = 2.0f, EPS = 1e-6f;

    __shared__ __align__(16) float raw[RPB][NC];   // RAW logits, 16 KB, wave-private regions

    const int wave = threadIdx.x >> 6;
    const int lane = threadIdx.x & 63;
    const int g    = lane >> 4;
    const int j    = lane & 15;
    const int q0   = blockIdx.x * RPB + wave * RPW;
    if (q0 >= NQ) return;               // wave-uniform (chunk 56, waves 1-3); all iters
    const int wr0  = wave * RPW;
    const int t0   = lane * 2;

    int qg = q0 + g; qg = qg < NQ - 1 ? qg : NQ - 1;   // tail clamp (load only)

    // persistent loop: this block's chunk, batches b0, b0+8, ..., b0+56
    for (int b = blockIdx.y; b < BB; b += GRIDY) {
        const size_t rowbase = (size_t)b * NQ;

        // ---- issue this iteration's global loads up front ----
        const float* lrow = logits + (rowbase + qg) * NC + j * 4;
        const float4 v0 = *reinterpret_cast<const float4*>(lrow);
        const float4 v1 = *reinterpret_cast<const float4*>(lrow + 64);
        const float4 v2 = *reinterpret_cast<const float4*>(lrow + 128);
        const float4 v3 = *reinterpret_cast<const float4*>(lrow + 192);

        float4 pb[RPW];
        #pragma unroll
        for (int r = 0; r < RPW; ++r)
            pb[r] = *reinterpret_cast<const float4*>(pboxes + (rowbase + q0 + r) * 4);

        const int2   lbl = *reinterpret_cast<const int2*>(tlabels + b * NT + t0);
        const float4 ta  = *reinterpret_cast<const float4*>(tboxes + ((size_t)b * NT + t0) * 4);
        const float4 tbv = *reinterpret_cast<const float4*>(tboxes + ((size_t)b * NT + t0 + 1) * 4);

        // ---- stash RAW logits to LDS (wave-private; lgkmcnt-ordered vs gathers) ----
        float* srow = &raw[wr0 + g][j * 4];
        *reinterpret_cast<float4*>(srow)       = v0;
        *reinterpret_cast<float4*>(srow + 64)  = v1;
        *reinterpret_cast<float4*>(srow + 128) = v2;
        *reinterpret_cast<float4*>(srow + 192) = v3;

        // ---- label gathers of raw logits ----
        float ga[RPW], gb[RPW];
        #pragma unroll
        for (int r = 0; r < RPW; ++r) {
            ga[r] = raw[wr0 + r][lbl.x];
            gb[r] = raw[wr0 + r][lbl.y];
        }

        // ---- exp + tree + DPP butterfly (VALU pipe only) ----
        float s = (((__expf(v0.x) + __expf(v0.y)) + (__expf(v0.z) + __expf(v0.w)))
                +  ((__expf(v1.x) + __expf(v1.y)) + (__expf(v1.z) + __expf(v1.w))))
                + (((__expf(v2.x) + __expf(v2.y)) + (__expf(v2.z) + __expf(v2.w)))
                +  ((__expf(v3.x) + __expf(v3.y)) + (__expf(v3.z) + __expf(v3.w))));
        s = dpp_add<0xB1>(s);   // quad_perm xor1
        s = dpp_add<0x4E>(s);   // quad_perm xor2
        s = dpp_add<0x141>(s);  // row_half_mirror (sum of 8)
        s = dpp_add<0x140>(s);  // row_mirror      (sum of 16)

        const float inv[RPW] = {
            __builtin_amdgcn_rcpf(lane_bcast(s, 0)),
            __builtin_amdgcn_rcpf(lane_bcast(s, 16)),
            __builtin_amdgcn_rcpf(lane_bcast(s, 32)),
            __builtin_amdgcn_rcpf(lane_bcast(s, 48)) };

        // ---- per-lane target constants ----
        const float ax1 = ta.x - 0.5f * ta.z, ay1 = ta.y - 0.5f * ta.w;
        const float ax2 = ta.x + 0.5f * ta.z, ay2 = ta.y + 0.5f * ta.w;
        const float aarea = fmaxf(ax2 - ax1, 0.0f) * fmaxf(ay2 - ay1, 0.0f);
        const float bx1 = tbv.x - 0.5f * tbv.z, by1 = tbv.y - 0.5f * tbv.w;
        const float bx2 = tbv.x + 0.5f * tbv.z, by2 = tbv.y + 0.5f * tbv.w;
        const float barea = fmaxf(bx2 - bx1, 0.0f) * fmaxf(by2 - by1, 0.0f);

        // ---- per row: prob at gather time, box costs, NT float2 store ----
        #pragma unroll
        for (int r = 0; r < RPW; ++r) {
            const float p0 = __expf(ga[r]) * inv[r];
            const float p1 = __expf(gb[r]) * inv[r];

            const float px1 = pb[r].x - 0.5f * pb[r].z, py1 = pb[r].y - 0.5f * pb[r].w;
            const float px2 = pb[r].x + 0.5f * pb[r].z, py2 = pb[r].y + 0.5f * pb[r].w;
            const float parea = fmaxf(px2 - px1, 0.0f) * fmaxf(py2 - py1, 0.0f);

            // target A
            const float l1a = fabsf(pb[r].x - ta.x) + fabsf(pb[r].y - ta.y)
                            + fabsf(pb[r].z - ta.z) + fabsf(pb[r].w - ta.w);
            const float ia  = fmaxf(fminf(px2, ax2) - fmaxf(px1, ax1), 0.0f)
                            * fmaxf(fminf(py2, ay2) - fmaxf(py1, ay1), 0.0f);
            const float ua  = parea + aarea - ia + EPS;
            const float ea  = fmaxf(fmaxf(px2, ax2) - fminf(px1, ax1), 0.0f)
                            * fmaxf(fmaxf(py2, ay2) - fminf(py1, ay1), 0.0f) + EPS;
            const float gioua = ia * __builtin_amdgcn_rcpf(ua)
                              - (ea - ua) * __builtin_amdgcn_rcpf(ea);
            const float c0 = -p0 + W_BBOX * l1a - W_GIOU * gioua;

            // target B
            const float l1b = fabsf(pb[r].x - tbv.x) + fabsf(pb[r].y - tbv.y)
                            + fabsf(pb[r].z - tbv.z) + fabsf(pb[r].w - tbv.w);
            const float ib  = fmaxf(fminf(px2, bx2) - fmaxf(px1, bx1), 0.0f)
                            * fmaxf(fminf(py2, by2) - fmaxf(py1, by1), 0.0f);
            const float ub  = parea + barea - ib + EPS;
            const float eb  = fmaxf(fmaxf(px2, bx2) - fminf(px1, bx1), 0.0f)
                            * fmaxf(fmaxf(py2, by2) - fminf(py1, by1), 0.0f) + EPS;
            const float gioub = ib * __builtin_amdgcn_rcpf(ub)
                              - (eb - ub) * __builtin_amdgcn_rcpf(eb);
            const float c1 = -p1 + W_BBOX * l1b - W_GIOU * gioub;

            f32x2 cc; cc.x = c0; cc.y = c1;
            __builtin_nontemporal_store(cc,
                reinterpret_cast<f32x2*>(out + (rowbase + q0 + r) * NT + t0));
        }
    }
}

extern "C" void kernel_launch(void* const* d_in, const int* in_sizes, int n_in,
                              void* d_out, int out_size, void* d_ws, size_t ws_size,
                              hipStream_t stream) {
    const float* logits  = (const float*)d_in[0];
    const float* pboxes  = (const float*)d_in[1];
    const int*   tlabels = (const int*)d_in[2];
    const float* tboxes  = (const float*)d_in[3];
    float* out = (float*)d_out;

    dim3 grid(NCHUNK, GRIDY);
    matcher_kernel<<<grid, 256, 0, stream>>>(logits, pboxes, tlabels, tboxes, out);
}